// Round 2
// baseline (258.955 us; speedup 1.0000x reference)
//
#include <hip/hip_runtime.h>
#include <hip/hip_bf16.h>

// LocalAggregation: B=8, N=2048, K=32, D=64, C1=64, C2=128, R=0.15, EPS=1e-5
// f32 storage, bf16-ified values.
// Factored stats1 (validated R7-R10):
//   h1[row,c] = g[m,c] + dx*wx[c]+dy*wy[c]+dz*wz[c],  g = feat @ W1[3:]
//   sum1[c]   = SUM_m cnt[m] g[m,c] + wx M1x + wy M1y + wz M1z
//   sumsq1[c] = SUM_m cnt g^2 + 2(wx A3x + wy A3y + wz A3z) + quadratic moments
// R12: kP v5 — 256 blocks x 1024 thr, u32 2^22 fixed-point LDS accumulators.
// R13: kD v3 — register-pressure fix. R8 kD logically held ~220 live values
//   (Bf 64 + meta 80 + staging) in 124 VGPRs -> compiler spill/remat, 208
//   scalar VMEM loads/thread setup; counters showed the stall (MfmaUtil 5.7%,
//   VALUBusy 20%, Occ 16.6%). Now: W2 staged in LDS as bf16 [n][72-padded]
//   (one ds_read_b128 per B-fragment, nt-outer loop, acc transient), meta
//   loads vectorized f32x4, idx hoisted for all 4 sites, centers via
//   readfirstlane (scalar loads), launch_bounds(256,3), setprio around MFMA.
// gamma2>0 => max-pool commutes with bn2+relu (k45).

#define BB 8
#define NN 2048
#define KK 32
#define DD 64
#define CC1 64
#define CC2 128
#define TOTROWS (BB*NN*KK) // 524288
#define SITES (BB*NN)      // 16384
#define PSLICES 256        // partial sets (kP blocks)

typedef __bf16 bf16x8 __attribute__((ext_vector_type(8)));
typedef float  f32x4  __attribute__((ext_vector_type(4)));

__device__ __forceinline__ void lds_add(float* p, float v) {
  __hip_atomic_fetch_add(p, v, __ATOMIC_RELAXED, __HIP_MEMORY_SCOPE_WORKGROUP);
}

// ---------------- K1: ball query, ballot compaction ----------------
// 512 blocks x 256 thr; block = (batch, 32-query group), wave = 8 queries.
__global__ __launch_bounds__(256) void k1_ball(const float* __restrict__ pos,
                                               int* __restrict__ idx)
{
  __shared__ float4 P[NN];  // 32 KB: x,y,z,S
  const int b = blockIdx.x >> 6;
  const int qbase = (blockIdx.x & 63) * 32;
  for (int i = threadIdx.x; i < NN; i += 256) {
    const float* p = pos + ((size_t)b*NN + i)*3;
    float x = p[0], y = p[1], z = p[2];
    float s = __fadd_rn(__fadd_rn(__fmul_rn(x,x), __fmul_rn(y,y)), __fmul_rn(z,z));
    P[i] = make_float4(x, y, z, s);
  }
  __syncthreads();
  const int wave = threadIdx.x >> 6, lane = threadIdx.x & 63;
  const float R2 = (float)(0.15 * 0.15);
  const unsigned long long lt = (lane == 63) ? 0x7fffffffffffffffull
                                             : ((1ull << lane) - 1ull);
  for (int qi = wave; qi < 32; qi += 4) {
    const int q = qbase + qi;
    const float4 Q = P[q];
    int* ip = idx + ((size_t)b*NN + q)*KK;
    int cnt = 0, first = -1;
    for (int step = 0; step < 32; ++step) {
      float4 p = P[step*64 + lane];
      float d = __fmul_rn(Q.x, p.x);
      d = fmaf(Q.y, p.y, d);
      d = fmaf(Q.z, p.z, d);
      float sq = __fsub_rn(__fadd_rn(Q.w, p.w), __fmul_rn(2.0f, d));
      bool in = !(sq > R2);
      unsigned long long mask = __ballot(in);
      if (first < 0 && mask) first = step*64 + (int)__builtin_ctzll(mask);
      int dst = cnt + (int)__popcll(mask & lt);
      if (in && dst < KK) ip[dst] = step*64 + lane;
      cnt += (int)__popcll(mask);
      if (cnt >= KK) break;
    }
    if (lane >= cnt && lane < KK) ip[lane] = first;  // cnt>=1 (self in ball)
  }
}

// ---------------- KP v5: per-m scatter, u32 LDS atomics, 1024 thr ----------------
// 256 blocks x 1024 thr; block = (batch, 64-site slice); thread = (site, k/2).
// Fixed point 2^22: per-block |sum dx| <= 2048 rows * 0.15 * 2^22 = 1.29e9 < 2^31.
// Padding (k>0 && m==ip0) aggregated into one add per thread.
__global__ __launch_bounds__(1024, 1) void kP_scatter(
    const float* __restrict__ pos, const int* __restrict__ idx,
    float* __restrict__ Pc, float* __restrict__ Px,
    float* __restrict__ Py, float* __restrict__ Pz,
    float* __restrict__ mom)
{
  __shared__ unsigned int Sc[NN], Sx[NN], Sy[NN], Sz[NN]; // 32 KB
  __shared__ float mred[16*9];
  const int b = blockIdx.x >> 5;       // 32 slices per batch
  const int slice = blockIdx.x & 31;   // 64 sites each
  for (int i = threadIdx.x; i < NN; i += 1024) {
    Sc[i] = 0u; Sx[i] = 0u; Sy[i] = 0u; Sz[i] = 0u;
  }
  __syncthreads();
  const float* pb = pos + (size_t)b*NN*3;
  const int sl = threadIdx.x >> 4;     // site-local 0..63
  const int kg = threadIdx.x & 15;     // k-group: 2 k's each
  const int site = slice*64 + sl;
  const int* ip = idx + ((size_t)(b*NN + site))*KK;
  const int ip0 = ip[0];
  const float cx = pb[site*3], cy = pb[site*3+1], cz = pb[site*3+2];
  const float FS = 4194304.0f;         // 2^22
  float m1x=0.f,m1y=0.f,m1z=0.f,mxx=0.f,myy=0.f,mzz=0.f,mxy=0.f,mxz=0.f,myz=0.f;
  int wt = 0;
  #pragma unroll
  for (int j = 0; j < 2; ++j) {
    const int k = kg*2 + j;
    const int m = ip[k];
    float dx = pb[m*3  ] - cx;
    float dy = pb[m*3+1] - cy;
    float dz = pb[m*3+2] - cz;
    if (k > 0 && m == ip0) {
      ++wt;                             // padding: aggregate
    } else {
      atomicAdd(&Sc[m], 1u);            // ds_add_u32
      atomicAdd(&Sx[m], (unsigned int)__float2int_rn(dx*FS));
      atomicAdd(&Sy[m], (unsigned int)__float2int_rn(dy*FS));
      atomicAdd(&Sz[m], (unsigned int)__float2int_rn(dz*FS));
    }
    m1x += dx; m1y += dy; m1z += dz;    // moments include padding rows
    mxx = fmaf(dx,dx,mxx); myy = fmaf(dy,dy,myy); mzz = fmaf(dz,dz,mzz);
    mxy = fmaf(dx,dy,mxy); mxz = fmaf(dx,dz,mxz); myz = fmaf(dy,dz,myz);
  }
  if (wt > 0) {
    float dx0 = pb[ip0*3  ] - cx;
    float dy0 = pb[ip0*3+1] - cy;
    float dz0 = pb[ip0*3+2] - cz;
    atomicAdd(&Sc[ip0], (unsigned int)wt);
    atomicAdd(&Sx[ip0], (unsigned int)(wt*__float2int_rn(dx0*FS)));
    atomicAdd(&Sy[ip0], (unsigned int)(wt*__float2int_rn(dy0*FS)));
    atomicAdd(&Sz[ip0], (unsigned int)(wt*__float2int_rn(dz0*FS)));
  }
  // per-wave moment reduce -> LDS (avoids 4096 global atomics per address)
  const int lane = threadIdx.x & 63;
  const int wv = threadIdx.x >> 6;     // 0..15
  float vals[9] = {m1x,m1y,m1z,mxx,myy,mzz,mxy,mxz,myz};
  #pragma unroll
  for (int i = 0; i < 9; ++i) {
    float v = vals[i];
    #pragma unroll
    for (int s = 1; s < 64; s <<= 1) v += __shfl_xor(v, s, 64);
    if (lane == 0) mred[wv*9 + i] = v;
  }
  __syncthreads();
  const float IS = 2.38418579101562500e-7f;  // 2^-22
  float* pc = Pc + (size_t)blockIdx.x*NN;
  float* px = Px + (size_t)blockIdx.x*NN;
  float* py = Py + (size_t)blockIdx.x*NN;
  float* pz = Pz + (size_t)blockIdx.x*NN;
  for (int i = threadIdx.x; i < NN; i += 1024) {
    pc[i] = (float)Sc[i];
    px[i] = (float)(int)Sx[i] * IS;
    py[i] = (float)(int)Sy[i] * IS;
    pz[i] = (float)(int)Sz[i] * IS;
  }
  if (threadIdx.x < 9) {
    float s = 0.f;
    #pragma unroll
    for (int w2 = 0; w2 < 16; ++w2) s += mred[w2*9 + threadIdx.x];
    unsafeAtomicAdd(&mom[threadIdx.x], s);
  }
}

// ---------------- KR: reduce 32 partials/batch -> cnt/DXa/DYa/DZa ----------------
// 256 blocks x 256 thr; i in [0,65536): a = array, j = b*2048+m.
__global__ __launch_bounds__(256) void kR_reduce(
    const float* __restrict__ Pc, const float* __restrict__ Px,
    const float* __restrict__ Py, const float* __restrict__ Pz,
    float* __restrict__ cnt, float* __restrict__ DXa,
    float* __restrict__ DYa, float* __restrict__ DZa)
{
  int i = blockIdx.x*256 + threadIdx.x;
  int a = i >> 14;              // 0..3
  int j = i & 16383;            // b*2048 + m
  int b = j >> 11, m = j & (NN-1);
  const float* P = (a == 0) ? Pc : (a == 1) ? Px : (a == 2) ? Py : Pz;
  float s = 0.f;
  #pragma unroll
  for (int sl = 0; sl < 32; ++sl) s += P[(size_t)(b*32 + sl)*NN + m];
  float* O = (a == 0) ? cnt : (a == 1) ? DXa : (a == 2) ? DYa : DZa;
  O[j] = s;
}

// ---------------- KB: g = feat @ W1[3:] via MFMA, fused A-sums ----------------
// 128 blocks x 256 thr -> 512 waves x 2 M-tiles (16 rows each).
// A layout: [0:64) Sum cnt*g, [64:128) Sum cnt*g^2, [128:192) Sum g*DX,
//           [192:256) Sum g*DY, [256:320) Sum g*DZ
__global__ __launch_bounds__(256) void kB_g(const float* __restrict__ feat,
                                            const float* __restrict__ W1,
                                            const float* __restrict__ cnt,
                                            const float* __restrict__ DXa,
                                            const float* __restrict__ DYa,
                                            const float* __restrict__ DZa,
                                            float* __restrict__ g,
                                            float* __restrict__ A)
{
  __shared__ float red[320];
  for (int i = threadIdx.x; i < 320; i += 256) red[i] = 0.f;
  __syncthreads();
  const int lane = threadIdx.x & 63;
  const int quad = lane >> 4;
  const int col  = lane & 15;
  const int gw = (blockIdx.x*256 + threadIdx.x) >> 6;   // 0..511

  bf16x8 Bf[2][4];
  #pragma unroll
  for (int kt = 0; kt < 2; ++kt)
    #pragma unroll
    for (int nt = 0; nt < 4; ++nt) {
      bf16x8 v;
      #pragma unroll
      for (int j = 0; j < 8; ++j)
        v[j] = (__bf16)W1[(3 + kt*32 + quad*8 + j)*CC1 + nt*16 + col];
      Bf[kt][nt] = v;
    }
  float a1[4], a2[4], a3[4], a4[4], a5[4];
  #pragma unroll
  for (int nt = 0; nt < 4; ++nt) { a1[nt]=0.f; a2[nt]=0.f; a3[nt]=0.f; a4[nt]=0.f; a5[nt]=0.f; }

  for (int t = 0; t < 2; ++t) {
    const int row0 = (gw*2 + t) * 16;
    bf16x8 Af[2];
    #pragma unroll
    for (int kt = 0; kt < 2; ++kt) {
      const float4* fp =
        (const float4*)(feat + (size_t)(row0 + col)*DD + kt*32 + quad*8);
      float4 f0 = fp[0], f1 = fp[1];
      float fv[8] = {f0.x,f0.y,f0.z,f0.w,f1.x,f1.y,f1.z,f1.w};
      bf16x8 v;
      #pragma unroll
      for (int j = 0; j < 8; ++j) v[j] = (__bf16)fv[j];
      Af[kt] = v;
    }
    float cw[4], dxw[4], dyw[4], dzw[4];
    #pragma unroll
    for (int r = 0; r < 4; ++r) {
      int row = row0 + quad*4 + r;
      cw[r] = cnt[row]; dxw[r] = DXa[row]; dyw[r] = DYa[row]; dzw[r] = DZa[row];
    }
    #pragma unroll
    for (int nt = 0; nt < 4; ++nt) {
      f32x4 a = {0.f, 0.f, 0.f, 0.f};
      a = __builtin_amdgcn_mfma_f32_16x16x32_bf16(Af[0], Bf[0][nt], a, 0, 0, 0);
      a = __builtin_amdgcn_mfma_f32_16x16x32_bf16(Af[1], Bf[1][nt], a, 0, 0, 0);
      #pragma unroll
      for (int r = 0; r < 4; ++r) {
        float v = a[r];
        g[(size_t)(row0 + quad*4 + r)*CC1 + nt*16 + col] = v;
        float cv = cw[r]*v;
        a1[nt] += cv; a2[nt] = fmaf(cv, v, a2[nt]);
        a3[nt] = fmaf(dxw[r], v, a3[nt]);
        a4[nt] = fmaf(dyw[r], v, a4[nt]);
        a5[nt] = fmaf(dzw[r], v, a5[nt]);
      }
    }
  }
  #pragma unroll
  for (int nt = 0; nt < 4; ++nt) {
    float v1=a1[nt], v2=a2[nt], v3=a3[nt], v4=a4[nt], v5=a5[nt];
    v1 += __shfl_xor(v1,16,64); v1 += __shfl_xor(v1,32,64);
    v2 += __shfl_xor(v2,16,64); v2 += __shfl_xor(v2,32,64);
    v3 += __shfl_xor(v3,16,64); v3 += __shfl_xor(v3,32,64);
    v4 += __shfl_xor(v4,16,64); v4 += __shfl_xor(v4,32,64);
    v5 += __shfl_xor(v5,16,64); v5 += __shfl_xor(v5,32,64);
    if (quad == 0) {
      int ch = nt*16 + col;
      lds_add(&red[ch], v1);
      lds_add(&red[64+ch], v2);
      lds_add(&red[128+ch], v3);
      lds_add(&red[192+ch], v4);
      lds_add(&red[256+ch], v5);
    }
  }
  __syncthreads();
  for (int i = threadIdx.x; i < 320; i += 256) unsafeAtomicAdd(&A[i], red[i]);
}

// ---------------- KS: assemble stats1 -> sc1, sh1, W1s ----------------
__global__ __launch_bounds__(256) void kS_fold(
    const float* __restrict__ W1, const float* __restrict__ gamma1,
    const float* __restrict__ beta1, const float* __restrict__ A,
    const float* __restrict__ mom,
    float* __restrict__ sc1, float* __restrict__ sh1, float* __restrict__ W1s)
{
  int c = threadIdx.x;
  if (c >= CC1) return;
  float wx = W1[c], wy = W1[CC1+c], wz = W1[2*CC1+c];
  float A1 = A[c], A2 = A[64+c], A3x = A[128+c], A3y = A[192+c], A3z = A[256+c];
  float sum1 = A1 + wx*mom[0] + wy*mom[1] + wz*mom[2];
  float ss = A2 + 2.f*(wx*A3x + wy*A3y + wz*A3z)
           + wx*wx*mom[3] + wy*wy*mom[4] + wz*wz*mom[5]
           + 2.f*(wx*wy*mom[6] + wx*wz*mom[7] + wy*wz*mom[8]);
  const float invN = 1.0f / (float)TOTROWS;
  float mean = sum1 * invN;
  float var  = ss * invN - mean*mean;
  float sc = rsqrtf(var + 1e-5f) * gamma1[c];
  float sh = beta1[c] - mean * sc;
  sc1[c] = sc; sh1[c] = sh;
  W1s[c] = wx*sc; W1s[64+c] = wy*sc; W1s[128+c] = wz*sc;
}

// ---------------- KD v3: MFMA main pass (BN1 inline), LDS-staged W2 ----------------
// 1024 blocks x 256 thr -> 4096 waves x 4 sites. Per site A1(32x64 bf16) @ W2(64x128).
// a = relu(g*sc + dx*wxs + dy*wys + dz*wzs + sh).
// W2 in LDS as bf16, [n][k] with rows padded to 72 (start banks 4*((col+quad)&7)
// -> uniform over 8 groups, no pathological conflict). nt-outer loop keeps the
// accumulator transient (4 VGPR); B-fragments are 2 ds_read_b128 per nt.
__global__ __launch_bounds__(256, 3) void kD_mfma(
    const float* __restrict__ pos, const int* __restrict__ idx,
    const float* __restrict__ g, const float* __restrict__ sc1,
    const float* __restrict__ sh1, const float* __restrict__ W1s,
    const float* __restrict__ W2,
    float* __restrict__ stats2, float* __restrict__ out_nf)
{
  __shared__ __bf16 W2T[128*72];   // 18 KB, [n][k] padded
  __shared__ float red2[256];
  red2[threadIdx.x] = 0.f;
  // cooperative fill: i = k*128+n (coalesced global reads)
  for (int i = threadIdx.x; i < CC1*CC2; i += 256) {
    int k = i >> 7, n = i & 127;
    W2T[n*72 + k] = (__bf16)W2[i];
  }
  __syncthreads();

  const int lane = threadIdx.x & 63;
  const int quad = lane >> 4;
  const int col  = lane & 15;
  const int gw = (blockIdx.x*256 + threadIdx.x) >> 6;

  // hoisted per-channel meta, vectorized (c0 = kt*32 + quad*8, 32B aligned)
  float wxs[2][8], wys[2][8], wzs[2][8], scj[2][8], shj[2][8];
  #pragma unroll
  for (int kt = 0; kt < 2; ++kt) {
    const int c0 = kt*32 + quad*8;
    f32x4 x0 = *(const f32x4*)&W1s[c0],       x1 = *(const f32x4*)&W1s[c0+4];
    f32x4 y0 = *(const f32x4*)&W1s[64+c0],    y1 = *(const f32x4*)&W1s[64+c0+4];
    f32x4 z0 = *(const f32x4*)&W1s[128+c0],   z1 = *(const f32x4*)&W1s[128+c0+4];
    f32x4 s0 = *(const f32x4*)&sc1[c0],       s1 = *(const f32x4*)&sc1[c0+4];
    f32x4 h0 = *(const f32x4*)&sh1[c0],       h1 = *(const f32x4*)&sh1[c0+4];
    #pragma unroll
    for (int j = 0; j < 4; ++j) {
      wxs[kt][j] = x0[j]; wxs[kt][4+j] = x1[j];
      wys[kt][j] = y0[j]; wys[kt][4+j] = y1[j];
      wzs[kt][j] = z0[j]; wzs[kt][4+j] = z1[j];
      scj[kt][j] = s0[j]; scj[kt][4+j] = s1[j];
      shj[kt][j] = h0[j]; shj[kt][4+j] = h1[j];
    }
  }

  // hoist idx for all 4 sites (one dependent round, issued together)
  int mm[4][2];
  #pragma unroll
  for (int si = 0; si < 4; ++si) {
    #pragma unroll
    for (int mt = 0; mt < 2; ++mt)
      mm[si][mt] = idx[(size_t)(gw*4 + si)*KK + mt*16 + col];
  }

  float ssum[8], ssq[8];
  #pragma unroll
  for (int nt = 0; nt < 8; ++nt) { ssum[nt] = 0.f; ssq[nt] = 0.f; }

  #pragma unroll
  for (int si = 0; si < 4; ++si) {
    const int site = __builtin_amdgcn_readfirstlane(gw*4 + si);
    const int b = site >> 11;
    const float cx = pos[(size_t)site*3];
    const float cy = pos[(size_t)site*3+1];
    const float cz = pos[(size_t)site*3+2];
    bf16x8 Af[2][2];
    #pragma unroll
    for (int mt = 0; mt < 2; ++mt) {
      const int m = mm[si][mt];
      const float* pm = pos + ((size_t)b*NN + m)*3;
      const float dx = pm[0]-cx, dy = pm[1]-cy, dz = pm[2]-cz;
      const float* gr = g + ((size_t)b*NN + m)*CC1 + quad*8;
      f32x4 ga = *(const f32x4*)gr,        gb = *(const f32x4*)(gr+4);
      f32x4 gc = *(const f32x4*)(gr+32),   gd = *(const f32x4*)(gr+36);
      float hv0[8] = {ga.x,ga.y,ga.z,ga.w,gb.x,gb.y,gb.z,gb.w};
      float hv1[8] = {gc.x,gc.y,gc.z,gc.w,gd.x,gd.y,gd.z,gd.w};
      bf16x8 v0, v1;
      #pragma unroll
      for (int j = 0; j < 8; ++j) {
        float t0 = fmaf(dz, wzs[0][j],
                   fmaf(dy, wys[0][j],
                   fmaf(dx, wxs[0][j], shj[0][j])));
        float h0 = fmaf(hv0[j], scj[0][j], t0);
        v0[j] = (__bf16)fmaxf(h0, 0.f);
        float t1 = fmaf(dz, wzs[1][j],
                   fmaf(dy, wys[1][j],
                   fmaf(dx, wxs[1][j], shj[1][j])));
        float h1 = fmaf(hv1[j], scj[1][j], t1);
        v1[j] = (__bf16)fmaxf(h1, 0.f);
      }
      Af[mt][0] = v0; Af[mt][1] = v1;
    }
    __builtin_amdgcn_s_setprio(1);
    #pragma unroll
    for (int nt = 0; nt < 8; ++nt) {
      const bf16x8 B0 = *(const bf16x8*)&W2T[(nt*16 + col)*72 + quad*8];
      const bf16x8 B1 = *(const bf16x8*)&W2T[(nt*16 + col)*72 + 32 + quad*8];
      float mxv = -3.0e38f;
      #pragma unroll
      for (int mt = 0; mt < 2; ++mt) {
        f32x4 a = {0.f, 0.f, 0.f, 0.f};
        a = __builtin_amdgcn_mfma_f32_16x16x32_bf16(Af[mt][0], B0, a, 0, 0, 0);
        a = __builtin_amdgcn_mfma_f32_16x16x32_bf16(Af[mt][1], B1, a, 0, 0, 0);
        #pragma unroll
        for (int r = 0; r < 4; ++r) {
          float v = a[r];
          ssum[nt] += v; ssq[nt] = fmaf(v, v, ssq[nt]);
          mxv = fmaxf(mxv, v);
        }
      }
      mxv = fmaxf(mxv, __shfl_xor(mxv, 16, 64));
      mxv = fmaxf(mxv, __shfl_xor(mxv, 32, 64));
      if ((nt & 3) == quad)
        out_nf[(size_t)site*CC2 + nt*16 + col] = mxv;   // pre-BN pooled
    }
    __builtin_amdgcn_s_setprio(0);
  }
  #pragma unroll
  for (int nt = 0; nt < 8; ++nt) {
    float s = ssum[nt];
    s += __shfl_xor(s, 16, 64); s += __shfl_xor(s, 32, 64);
    float q = ssq[nt];
    q += __shfl_xor(q, 16, 64); q += __shfl_xor(q, 32, 64);
    if (lane < 16) {
      atomicAdd(&red2[nt*16 + col], s);
      atomicAdd(&red2[128 + nt*16 + col], q);
    }
  }
  __syncthreads();
  unsafeAtomicAdd(&stats2[threadIdx.x], red2[threadIdx.x]);
}

// ---------------- K45: position copy + bn2/relu in place ----------------
// blocks [0,192): copy position (49152 elems); blocks [192,8384): bn2.
__global__ __launch_bounds__(256) void k45_epi(const float* __restrict__ pos,
                                               const float* __restrict__ g2,
                                               const float* __restrict__ be2,
                                               const float* __restrict__ stats2,
                                               float* __restrict__ out)
{
  int i = blockIdx.x*256 + threadIdx.x;
  if (blockIdx.x < 192) { out[i] = pos[i]; return; }
  int j = i - 192*256;
  int c = j & (CC2-1);
  const float invc = 1.0f / (float)TOTROWS;
  float mean = stats2[c] * invc;
  float var  = stats2[128 + c] * invc - mean*mean;
  float sc = rsqrtf(var + 1e-5f) * g2[c];
  float sh = be2[c] - mean * sc;
  float* out_nf = out + (size_t)BB*NN*3;
  float x = out_nf[j];
  out_nf[j] = fmaxf(fmaf(x, sc, sh), 0.f);
}

extern "C" void kernel_launch(void* const* d_in, const int* in_sizes, int n_in,
                              void* d_out, int out_size, void* d_ws, size_t ws_size,
                              hipStream_t stream) {
  const float* pos  = (const float*)d_in[0];
  const float* feat = (const float*)d_in[1];
  const float* W1   = (const float*)d_in[2];
  const float* g1   = (const float*)d_in[3];
  const float* be1  = (const float*)d_in[4];
  const float* W2   = (const float*)d_in[5];
  const float* g2   = (const float*)d_in[6];
  const float* be2  = (const float*)d_in[7];
  float* out = (float*)d_out;
  float* out_nf = out + (size_t)BB*NN*3;

  char* w = (char*)d_ws;
  int*   idx    = (int*)w;                       // 2 MB @ 0
  float* A      = (float*)(w + 0x200000);        // 320
  float* mom    = A + 320;                       // 16
  float* stats2 = mom + 16;                      // 256
  float* sc1    = stats2 + 256;                  // 64
  float* sh1    = sc1 + 64;                      // 64
  float* W1s    = sh1 + 64;                      // 192
  float* cnt    = (float*)(w + 0x210000);        // 16384 each
  float* DXa    = cnt + SITES;
  float* DYa    = DXa + SITES;
  float* DZa    = DYa + SITES;
  // Partials: 256 sets x 2048 f32 = 2 MB each, 8 MB total @ 0x260000.
  // They ALIAS g (4 MB @ 0x260000): partials are dead after kR_reduce,
  // and g is written only afterwards by kB_g. Footprint unchanged (0xA60000).
  float* Pc     = (float*)(w + 0x260000);
  float* Px     = Pc + (size_t)PSLICES*NN;
  float* Py     = Px + (size_t)PSLICES*NN;
  float* Pz     = Py + (size_t)PSLICES*NN;       // ends 0xA60000
  float* g      = (float*)(w + 0x260000);        // 4 MB (reuses partial space)

  hipMemsetAsync(A, 0, (320 + 16 + 256)*sizeof(float), stream);
  k1_ball   <<<512, 256, 0, stream>>>(pos, idx);
  kP_scatter<<<256, 1024, 0, stream>>>(pos, idx, Pc, Px, Py, Pz, mom);
  kR_reduce <<<256, 256, 0, stream>>>(Pc, Px, Py, Pz, cnt, DXa, DYa, DZa);
  kB_g      <<<128, 256, 0, stream>>>(feat, W1, cnt, DXa, DYa, DZa, g, A);
  kS_fold   <<<1, 256, 0, stream>>>(W1, g1, be1, A, mom, sc1, sh1, W1s);
  kD_mfma   <<<1024, 256, 0, stream>>>(pos, idx, g, sc1, sh1, W1s, W2,
                                       stats2, out_nf);
  k45_epi   <<<192 + (SITES*CC2)/256, 256, 0, stream>>>(pos, g2, be2, stats2, out);
}

// Round 3
// 248.308 us; speedup vs baseline: 1.0429x; 1.0429x over previous
//
#include <hip/hip_runtime.h>
#include <hip/hip_bf16.h>

// LocalAggregation: B=8, N=2048, K=32, D=64, C1=64, C2=128, R=0.15, EPS=1e-5
// f32 storage, bf16-ified values.
// Factored stats1 (validated R7-R10):
//   h1[row,c] = g[m,c] + dx*wx[c]+dy*wy[c]+dz*wz[c],  g = feat @ W1[3:]
//   sum1[c]   = SUM_m cnt[m] g[m,c] + wx M1x + wy M1y + wz M1z
//   sumsq1[c] = SUM_m cnt g^2 + 2(wx A3x + wy A3y + wz A3z) + quadratic moments
// R12: kP v5 — 256 blocks x 1024 thr, u32 2^22 fixed-point LDS accumulators.
// R13 FAILED (121us): launch_bounds(256,3)+hoisted arrays+unroll/setprio ->
//   arrays spilled to scratch (WRITE_SIZE 9->170MB, VGPR 84). Lesson: scratch
//   traffic shows up as WRITE_SIZE; keep pipeline state in NAMED scalars.
// R14: kD v4 — R8 skeleton + (a) W2 in LDS [n][72] bf16 (nt-outer, transient
//   acc; kills 64-VGPR Bf + 128 setup loads/thread), (b) meta reloaded per
//   site via f32x4 (L1-hot) instead of 80 resident VGPRs, (c) single-buffer
//   software pipeline: BUILD(t) -> ISSUE(t+1) -> MFMA(t), so the g-gather
//   latency of site t+1 hides under site t's MFMA+reduce. launch_bounds(256,2),
//   no setprio, no readfirstlane, all pipeline state named scalars.
// gamma2>0 => max-pool commutes with bn2+relu (k45).

#define BB 8
#define NN 2048
#define KK 32
#define DD 64
#define CC1 64
#define CC2 128
#define TOTROWS (BB*NN*KK) // 524288
#define SITES (BB*NN)      // 16384
#define PSLICES 256        // partial sets (kP blocks)

typedef __bf16 bf16x8 __attribute__((ext_vector_type(8)));
typedef float  f32x4  __attribute__((ext_vector_type(4)));

__device__ __forceinline__ void lds_add(float* p, float v) {
  __hip_atomic_fetch_add(p, v, __ATOMIC_RELAXED, __HIP_MEMORY_SCOPE_WORKGROUP);
}

// ---------------- K1: ball query, ballot compaction ----------------
// 512 blocks x 256 thr; block = (batch, 32-query group), wave = 8 queries.
__global__ __launch_bounds__(256) void k1_ball(const float* __restrict__ pos,
                                               int* __restrict__ idx)
{
  __shared__ float4 P[NN];  // 32 KB: x,y,z,S
  const int b = blockIdx.x >> 6;
  const int qbase = (blockIdx.x & 63) * 32;
  for (int i = threadIdx.x; i < NN; i += 256) {
    const float* p = pos + ((size_t)b*NN + i)*3;
    float x = p[0], y = p[1], z = p[2];
    float s = __fadd_rn(__fadd_rn(__fmul_rn(x,x), __fmul_rn(y,y)), __fmul_rn(z,z));
    P[i] = make_float4(x, y, z, s);
  }
  __syncthreads();
  const int wave = threadIdx.x >> 6, lane = threadIdx.x & 63;
  const float R2 = (float)(0.15 * 0.15);
  const unsigned long long lt = (lane == 63) ? 0x7fffffffffffffffull
                                             : ((1ull << lane) - 1ull);
  for (int qi = wave; qi < 32; qi += 4) {
    const int q = qbase + qi;
    const float4 Q = P[q];
    int* ip = idx + ((size_t)b*NN + q)*KK;
    int cnt = 0, first = -1;
    for (int step = 0; step < 32; ++step) {
      float4 p = P[step*64 + lane];
      float d = __fmul_rn(Q.x, p.x);
      d = fmaf(Q.y, p.y, d);
      d = fmaf(Q.z, p.z, d);
      float sq = __fsub_rn(__fadd_rn(Q.w, p.w), __fmul_rn(2.0f, d));
      bool in = !(sq > R2);
      unsigned long long mask = __ballot(in);
      if (first < 0 && mask) first = step*64 + (int)__builtin_ctzll(mask);
      int dst = cnt + (int)__popcll(mask & lt);
      if (in && dst < KK) ip[dst] = step*64 + lane;
      cnt += (int)__popcll(mask);
      if (cnt >= KK) break;
    }
    if (lane >= cnt && lane < KK) ip[lane] = first;  // cnt>=1 (self in ball)
  }
}

// ---------------- KP v5: per-m scatter, u32 LDS atomics, 1024 thr ----------------
// 256 blocks x 1024 thr; block = (batch, 64-site slice); thread = (site, k/2).
// Fixed point 2^22: per-block |sum dx| <= 2048 rows * 0.15 * 2^22 = 1.29e9 < 2^31.
// Padding (k>0 && m==ip0) aggregated into one add per thread.
__global__ __launch_bounds__(1024, 1) void kP_scatter(
    const float* __restrict__ pos, const int* __restrict__ idx,
    float* __restrict__ Pc, float* __restrict__ Px,
    float* __restrict__ Py, float* __restrict__ Pz,
    float* __restrict__ mom)
{
  __shared__ unsigned int Sc[NN], Sx[NN], Sy[NN], Sz[NN]; // 32 KB
  __shared__ float mred[16*9];
  const int b = blockIdx.x >> 5;       // 32 slices per batch
  const int slice = blockIdx.x & 31;   // 64 sites each
  for (int i = threadIdx.x; i < NN; i += 1024) {
    Sc[i] = 0u; Sx[i] = 0u; Sy[i] = 0u; Sz[i] = 0u;
  }
  __syncthreads();
  const float* pb = pos + (size_t)b*NN*3;
  const int sl = threadIdx.x >> 4;     // site-local 0..63
  const int kg = threadIdx.x & 15;     // k-group: 2 k's each
  const int site = slice*64 + sl;
  const int* ip = idx + ((size_t)(b*NN + site))*KK;
  const int ip0 = ip[0];
  const float cx = pb[site*3], cy = pb[site*3+1], cz = pb[site*3+2];
  const float FS = 4194304.0f;         // 2^22
  float m1x=0.f,m1y=0.f,m1z=0.f,mxx=0.f,myy=0.f,mzz=0.f,mxy=0.f,mxz=0.f,myz=0.f;
  int wt = 0;
  #pragma unroll
  for (int j = 0; j < 2; ++j) {
    const int k = kg*2 + j;
    const int m = ip[k];
    float dx = pb[m*3  ] - cx;
    float dy = pb[m*3+1] - cy;
    float dz = pb[m*3+2] - cz;
    if (k > 0 && m == ip0) {
      ++wt;                             // padding: aggregate
    } else {
      atomicAdd(&Sc[m], 1u);            // ds_add_u32
      atomicAdd(&Sx[m], (unsigned int)__float2int_rn(dx*FS));
      atomicAdd(&Sy[m], (unsigned int)__float2int_rn(dy*FS));
      atomicAdd(&Sz[m], (unsigned int)__float2int_rn(dz*FS));
    }
    m1x += dx; m1y += dy; m1z += dz;    // moments include padding rows
    mxx = fmaf(dx,dx,mxx); myy = fmaf(dy,dy,myy); mzz = fmaf(dz,dz,mzz);
    mxy = fmaf(dx,dy,mxy); mxz = fmaf(dx,dz,mxz); myz = fmaf(dy,dz,myz);
  }
  if (wt > 0) {
    float dx0 = pb[ip0*3  ] - cx;
    float dy0 = pb[ip0*3+1] - cy;
    float dz0 = pb[ip0*3+2] - cz;
    atomicAdd(&Sc[ip0], (unsigned int)wt);
    atomicAdd(&Sx[ip0], (unsigned int)(wt*__float2int_rn(dx0*FS)));
    atomicAdd(&Sy[ip0], (unsigned int)(wt*__float2int_rn(dy0*FS)));
    atomicAdd(&Sz[ip0], (unsigned int)(wt*__float2int_rn(dz0*FS)));
  }
  // per-wave moment reduce -> LDS (avoids 4096 global atomics per address)
  const int lane = threadIdx.x & 63;
  const int wv = threadIdx.x >> 6;     // 0..15
  float vals[9] = {m1x,m1y,m1z,mxx,myy,mzz,mxy,mxz,myz};
  #pragma unroll
  for (int i = 0; i < 9; ++i) {
    float v = vals[i];
    #pragma unroll
    for (int s = 1; s < 64; s <<= 1) v += __shfl_xor(v, s, 64);
    if (lane == 0) mred[wv*9 + i] = v;
  }
  __syncthreads();
  const float IS = 2.38418579101562500e-7f;  // 2^-22
  float* pc = Pc + (size_t)blockIdx.x*NN;
  float* px = Px + (size_t)blockIdx.x*NN;
  float* py = Py + (size_t)blockIdx.x*NN;
  float* pz = Pz + (size_t)blockIdx.x*NN;
  for (int i = threadIdx.x; i < NN; i += 1024) {
    pc[i] = (float)Sc[i];
    px[i] = (float)(int)Sx[i] * IS;
    py[i] = (float)(int)Sy[i] * IS;
    pz[i] = (float)(int)Sz[i] * IS;
  }
  if (threadIdx.x < 9) {
    float s = 0.f;
    #pragma unroll
    for (int w2 = 0; w2 < 16; ++w2) s += mred[w2*9 + threadIdx.x];
    unsafeAtomicAdd(&mom[threadIdx.x], s);
  }
}

// ---------------- KR: reduce 32 partials/batch -> cnt/DXa/DYa/DZa ----------------
// 256 blocks x 256 thr; i in [0,65536): a = array, j = b*2048+m.
__global__ __launch_bounds__(256) void kR_reduce(
    const float* __restrict__ Pc, const float* __restrict__ Px,
    const float* __restrict__ Py, const float* __restrict__ Pz,
    float* __restrict__ cnt, float* __restrict__ DXa,
    float* __restrict__ DYa, float* __restrict__ DZa)
{
  int i = blockIdx.x*256 + threadIdx.x;
  int a = i >> 14;              // 0..3
  int j = i & 16383;            // b*2048 + m
  int b = j >> 11, m = j & (NN-1);
  const float* P = (a == 0) ? Pc : (a == 1) ? Px : (a == 2) ? Py : Pz;
  float s = 0.f;
  #pragma unroll
  for (int sl = 0; sl < 32; ++sl) s += P[(size_t)(b*32 + sl)*NN + m];
  float* O = (a == 0) ? cnt : (a == 1) ? DXa : (a == 2) ? DYa : DZa;
  O[j] = s;
}

// ---------------- KB: g = feat @ W1[3:] via MFMA, fused A-sums ----------------
// 128 blocks x 256 thr -> 512 waves x 2 M-tiles (16 rows each).
// A layout: [0:64) Sum cnt*g, [64:128) Sum cnt*g^2, [128:192) Sum g*DX,
//           [192:256) Sum g*DY, [256:320) Sum g*DZ
__global__ __launch_bounds__(256) void kB_g(const float* __restrict__ feat,
                                            const float* __restrict__ W1,
                                            const float* __restrict__ cnt,
                                            const float* __restrict__ DXa,
                                            const float* __restrict__ DYa,
                                            const float* __restrict__ DZa,
                                            float* __restrict__ g,
                                            float* __restrict__ A)
{
  __shared__ float red[320];
  for (int i = threadIdx.x; i < 320; i += 256) red[i] = 0.f;
  __syncthreads();
  const int lane = threadIdx.x & 63;
  const int quad = lane >> 4;
  const int col  = lane & 15;
  const int gw = (blockIdx.x*256 + threadIdx.x) >> 6;   // 0..511

  bf16x8 Bf[2][4];
  #pragma unroll
  for (int kt = 0; kt < 2; ++kt)
    #pragma unroll
    for (int nt = 0; nt < 4; ++nt) {
      bf16x8 v;
      #pragma unroll
      for (int j = 0; j < 8; ++j)
        v[j] = (__bf16)W1[(3 + kt*32 + quad*8 + j)*CC1 + nt*16 + col];
      Bf[kt][nt] = v;
    }
  float a1[4], a2[4], a3[4], a4[4], a5[4];
  #pragma unroll
  for (int nt = 0; nt < 4; ++nt) { a1[nt]=0.f; a2[nt]=0.f; a3[nt]=0.f; a4[nt]=0.f; a5[nt]=0.f; }

  for (int t = 0; t < 2; ++t) {
    const int row0 = (gw*2 + t) * 16;
    bf16x8 Af[2];
    #pragma unroll
    for (int kt = 0; kt < 2; ++kt) {
      const float4* fp =
        (const float4*)(feat + (size_t)(row0 + col)*DD + kt*32 + quad*8);
      float4 f0 = fp[0], f1 = fp[1];
      float fv[8] = {f0.x,f0.y,f0.z,f0.w,f1.x,f1.y,f1.z,f1.w};
      bf16x8 v;
      #pragma unroll
      for (int j = 0; j < 8; ++j) v[j] = (__bf16)fv[j];
      Af[kt] = v;
    }
    float cw[4], dxw[4], dyw[4], dzw[4];
    #pragma unroll
    for (int r = 0; r < 4; ++r) {
      int row = row0 + quad*4 + r;
      cw[r] = cnt[row]; dxw[r] = DXa[row]; dyw[r] = DYa[row]; dzw[r] = DZa[row];
    }
    #pragma unroll
    for (int nt = 0; nt < 4; ++nt) {
      f32x4 a = {0.f, 0.f, 0.f, 0.f};
      a = __builtin_amdgcn_mfma_f32_16x16x32_bf16(Af[0], Bf[0][nt], a, 0, 0, 0);
      a = __builtin_amdgcn_mfma_f32_16x16x32_bf16(Af[1], Bf[1][nt], a, 0, 0, 0);
      #pragma unroll
      for (int r = 0; r < 4; ++r) {
        float v = a[r];
        g[(size_t)(row0 + quad*4 + r)*CC1 + nt*16 + col] = v;
        float cv = cw[r]*v;
        a1[nt] += cv; a2[nt] = fmaf(cv, v, a2[nt]);
        a3[nt] = fmaf(dxw[r], v, a3[nt]);
        a4[nt] = fmaf(dyw[r], v, a4[nt]);
        a5[nt] = fmaf(dzw[r], v, a5[nt]);
      }
    }
  }
  #pragma unroll
  for (int nt = 0; nt < 4; ++nt) {
    float v1=a1[nt], v2=a2[nt], v3=a3[nt], v4=a4[nt], v5=a5[nt];
    v1 += __shfl_xor(v1,16,64); v1 += __shfl_xor(v1,32,64);
    v2 += __shfl_xor(v2,16,64); v2 += __shfl_xor(v2,32,64);
    v3 += __shfl_xor(v3,16,64); v3 += __shfl_xor(v3,32,64);
    v4 += __shfl_xor(v4,16,64); v4 += __shfl_xor(v4,32,64);
    v5 += __shfl_xor(v5,16,64); v5 += __shfl_xor(v5,32,64);
    if (quad == 0) {
      int ch = nt*16 + col;
      lds_add(&red[ch], v1);
      lds_add(&red[64+ch], v2);
      lds_add(&red[128+ch], v3);
      lds_add(&red[192+ch], v4);
      lds_add(&red[256+ch], v5);
    }
  }
  __syncthreads();
  for (int i = threadIdx.x; i < 320; i += 256) unsafeAtomicAdd(&A[i], red[i]);
}

// ---------------- KS: assemble stats1 -> sc1, sh1, W1s ----------------
__global__ __launch_bounds__(256) void kS_fold(
    const float* __restrict__ W1, const float* __restrict__ gamma1,
    const float* __restrict__ beta1, const float* __restrict__ A,
    const float* __restrict__ mom,
    float* __restrict__ sc1, float* __restrict__ sh1, float* __restrict__ W1s)
{
  int c = threadIdx.x;
  if (c >= CC1) return;
  float wx = W1[c], wy = W1[CC1+c], wz = W1[2*CC1+c];
  float A1 = A[c], A2 = A[64+c], A3x = A[128+c], A3y = A[192+c], A3z = A[256+c];
  float sum1 = A1 + wx*mom[0] + wy*mom[1] + wz*mom[2];
  float ss = A2 + 2.f*(wx*A3x + wy*A3y + wz*A3z)
           + wx*wx*mom[3] + wy*wy*mom[4] + wz*wz*mom[5]
           + 2.f*(wx*wy*mom[6] + wx*wz*mom[7] + wy*wz*mom[8]);
  const float invN = 1.0f / (float)TOTROWS;
  float mean = sum1 * invN;
  float var  = ss * invN - mean*mean;
  float sc = rsqrtf(var + 1e-5f) * gamma1[c];
  float sh = beta1[c] - mean * sc;
  sc1[c] = sc; sh1[c] = sh;
  W1s[c] = wx*sc; W1s[64+c] = wy*sc; W1s[128+c] = wz*sc;
}

// ---------------- KD v4 helpers ----------------
// Build two A-fragments (mt=a,b) for one kt from raw g vectors + meta loaded
// here (f32x4, L1-hot, 4 uniform addrs/wave) so meta is not resident state.
__device__ __forceinline__ void build2(
    f32x4 ua, f32x4 va, f32x4 ub, f32x4 vb,
    float dxa, float dya, float dza, float dxb, float dyb, float dzb,
    const float* __restrict__ mx, const float* __restrict__ my,
    const float* __restrict__ mz, const float* __restrict__ ms,
    const float* __restrict__ mh, bf16x8& outA, bf16x8& outB)
{
  f32x4 x0 = *(const f32x4*)mx, x1 = *(const f32x4*)(mx+4);
  f32x4 y0 = *(const f32x4*)my, y1 = *(const f32x4*)(my+4);
  f32x4 z0 = *(const f32x4*)mz, z1 = *(const f32x4*)(mz+4);
  f32x4 s0 = *(const f32x4*)ms, s1 = *(const f32x4*)(ms+4);
  f32x4 h0 = *(const f32x4*)mh, h1 = *(const f32x4*)(mh+4);
  bf16x8 A, Bv;
  #pragma unroll
  for (int j = 0; j < 8; ++j) {
    float wx = (j<4) ? x0[j] : x1[j-4];
    float wy = (j<4) ? y0[j] : y1[j-4];
    float wz = (j<4) ? z0[j] : z1[j-4];
    float sc = (j<4) ? s0[j] : s1[j-4];
    float sh = (j<4) ? h0[j] : h1[j-4];
    float ga = (j<4) ? ua[j] : va[j-4];
    float gb = (j<4) ? ub[j] : vb[j-4];
    float ta = fmaf(dza, wz, fmaf(dya, wy, fmaf(dxa, wx, sh)));
    A[j]  = (__bf16)fmaxf(fmaf(ga, sc, ta), 0.f);
    float tb = fmaf(dzb, wz, fmaf(dyb, wy, fmaf(dxb, wx, sh)));
    Bv[j] = (__bf16)fmaxf(fmaf(gb, sc, tb), 0.f);
  }
  outA = A; outB = Bv;
}

// MFMA + pooled-max + stats accumulation for one site. nt-outer, transient acc.
__device__ __forceinline__ void mfma_out(
    const __bf16 (&W2T)[CC2*72],
    bf16x8 A00, bf16x8 A01, bf16x8 A10, bf16x8 A11,
    int quad, int col, float* ssum, float* ssq, float* __restrict__ outp)
{
  #pragma unroll
  for (int nt = 0; nt < 8; ++nt) {
    const bf16x8 B0 = *(const bf16x8*)&W2T[(nt*16 + col)*72 + quad*8];
    const bf16x8 B1 = *(const bf16x8*)&W2T[(nt*16 + col)*72 + 32 + quad*8];
    float mxv = -3.0e38f;
    f32x4 a = {0.f, 0.f, 0.f, 0.f};
    a = __builtin_amdgcn_mfma_f32_16x16x32_bf16(A00, B0, a, 0, 0, 0);
    a = __builtin_amdgcn_mfma_f32_16x16x32_bf16(A01, B1, a, 0, 0, 0);
    #pragma unroll
    for (int r = 0; r < 4; ++r) {
      float v = a[r];
      ssum[nt] += v; ssq[nt] = fmaf(v, v, ssq[nt]); mxv = fmaxf(mxv, v);
    }
    f32x4 a2 = {0.f, 0.f, 0.f, 0.f};
    a2 = __builtin_amdgcn_mfma_f32_16x16x32_bf16(A10, B0, a2, 0, 0, 0);
    a2 = __builtin_amdgcn_mfma_f32_16x16x32_bf16(A11, B1, a2, 0, 0, 0);
    #pragma unroll
    for (int r = 0; r < 4; ++r) {
      float v = a2[r];
      ssum[nt] += v; ssq[nt] = fmaf(v, v, ssq[nt]); mxv = fmaxf(mxv, v);
    }
    mxv = fmaxf(mxv, __shfl_xor(mxv, 16, 64));
    mxv = fmaxf(mxv, __shfl_xor(mxv, 32, 64));
    if ((nt & 3) == quad) outp[nt*16 + col] = mxv;   // pre-BN pooled
  }
}

// ---------------- KD v4: MFMA main pass (BN1 inline), LDS W2, pipelined ----------------
// 1024 blocks x 256 thr -> 4096 waves x 4 sites. Per site A1(32x64 bf16) @ W2(64x128).
// Pipeline: BUILD(t) consumes g-regs -> ISSUE(t+1) refills them (no wait) ->
// MFMA(t). The vmcnt wait for site t+1 lands after site t's MFMA+reduce.
__global__ __launch_bounds__(256, 2) void kD_mfma(
    const float* __restrict__ pos, const int* __restrict__ idx,
    const float* __restrict__ g, const float* __restrict__ sc1,
    const float* __restrict__ sh1, const float* __restrict__ W1s,
    const float* __restrict__ W2,
    float* __restrict__ stats2, float* __restrict__ out_nf)
{
  __shared__ __bf16 W2T[CC2*72];   // 18 KB, [n][k] padded to 72
  __shared__ float red2[256];
  red2[threadIdx.x] = 0.f;
  for (int i = threadIdx.x; i < CC1*CC2; i += 256) {
    int k = i >> 7, n = i & 127;
    W2T[n*72 + k] = (__bf16)W2[i];
  }
  __syncthreads();

  const int lane = threadIdx.x & 63;
  const int quad = lane >> 4;
  const int col  = lane & 15;
  const int gw = (blockIdx.x*256 + threadIdx.x) >> 6;
  const int site0 = gw*4;            // 4 sites, same batch (4 | 2048)
  const int b = site0 >> 11;
  const int ls0 = site0 & (NN-1);
  const float* gbase = g + (size_t)b*NN*CC1;
  const float* pb = pos + (size_t)b*NN*3;
  const int* ip = idx + (size_t)site0*KK;

  // hoist idx for all 4 sites (independent loads, issued together)
  const int mm0a = ip[col],          mm0b = ip[16+col];
  const int mm1a = ip[KK+col],       mm1b = ip[KK+16+col];
  const int mm2a = ip[2*KK+col],     mm2b = ip[2*KK+16+col];
  const int mm3a = ip[3*KK+col],     mm3b = ip[3*KK+16+col];

  float ssum[8], ssq[8];
  #pragma unroll
  for (int nt = 0; nt < 8; ++nt) { ssum[nt] = 0.f; ssq[nt] = 0.f; }

  // pipeline state: single g buffer + neighbor/center positions + A-fragments
  f32x4 gA0, gA1, gA2, gA3, gB0, gB1, gB2, gB3;
  float nax, nay, naz, nbx, nby, nbz, ccx, ccy, ccz;
  bf16x8 A00, A01, A10, A11;   // A<mt><kt>

#define KD_ISSUE(T, MA, MB) { \
    const float* ra_ = gbase + (size_t)(MA)*CC1 + quad*8; \
    const float* rb_ = gbase + (size_t)(MB)*CC1 + quad*8; \
    gA0 = *(const f32x4*)ra_;      gA1 = *(const f32x4*)(ra_+4); \
    gA2 = *(const f32x4*)(ra_+32); gA3 = *(const f32x4*)(ra_+36); \
    gB0 = *(const f32x4*)rb_;      gB1 = *(const f32x4*)(rb_+4); \
    gB2 = *(const f32x4*)(rb_+32); gB3 = *(const f32x4*)(rb_+36); \
    nax = pb[(MA)*3]; nay = pb[(MA)*3+1]; naz = pb[(MA)*3+2]; \
    nbx = pb[(MB)*3]; nby = pb[(MB)*3+1]; nbz = pb[(MB)*3+2]; \
    ccx = pb[(ls0+(T))*3]; ccy = pb[(ls0+(T))*3+1]; ccz = pb[(ls0+(T))*3+2]; }

#define KD_BUILD() { \
    float dxa = nax-ccx, dya = nay-ccy, dza = naz-ccz; \
    float dxb = nbx-ccx, dyb = nby-ccy, dzb = nbz-ccz; \
    build2(gA0,gA1, gB0,gB1, dxa,dya,dza, dxb,dyb,dzb, \
           W1s+quad*8, W1s+64+quad*8, W1s+128+quad*8, \
           sc1+quad*8, sh1+quad*8, A00, A10); \
    build2(gA2,gA3, gB2,gB3, dxa,dya,dza, dxb,dyb,dzb, \
           W1s+32+quad*8, W1s+96+quad*8, W1s+160+quad*8, \
           sc1+32+quad*8, sh1+32+quad*8, A01, A11); }

  KD_ISSUE(0, mm0a, mm0b);
  KD_BUILD();
  KD_ISSUE(1, mm1a, mm1b);
  mfma_out(W2T, A00, A01, A10, A11, quad, col, ssum, ssq,
           out_nf + (size_t)(site0+0)*CC2);
  KD_BUILD();
  KD_ISSUE(2, mm2a, mm2b);
  mfma_out(W2T, A00, A01, A10, A11, quad, col, ssum, ssq,
           out_nf + (size_t)(site0+1)*CC2);
  KD_BUILD();
  KD_ISSUE(3, mm3a, mm3b);
  mfma_out(W2T, A00, A01, A10, A11, quad, col, ssum, ssq,
           out_nf + (size_t)(site0+2)*CC2);
  KD_BUILD();
  mfma_out(W2T, A00, A01, A10, A11, quad, col, ssum, ssq,
           out_nf + (size_t)(site0+3)*CC2);

#undef KD_ISSUE
#undef KD_BUILD

  #pragma unroll
  for (int nt = 0; nt < 8; ++nt) {
    float s = ssum[nt];
    s += __shfl_xor(s, 16, 64); s += __shfl_xor(s, 32, 64);
    float q = ssq[nt];
    q += __shfl_xor(q, 16, 64); q += __shfl_xor(q, 32, 64);
    if (lane < 16) {
      atomicAdd(&red2[nt*16 + col], s);
      atomicAdd(&red2[128 + nt*16 + col], q);
    }
  }
  __syncthreads();
  unsafeAtomicAdd(&stats2[threadIdx.x], red2[threadIdx.x]);
}

// ---------------- K45: position copy + bn2/relu in place ----------------
// blocks [0,192): copy position (49152 elems); blocks [192,8384): bn2.
__global__ __launch_bounds__(256) void k45_epi(const float* __restrict__ pos,
                                               const float* __restrict__ g2,
                                               const float* __restrict__ be2,
                                               const float* __restrict__ stats2,
                                               float* __restrict__ out)
{
  int i = blockIdx.x*256 + threadIdx.x;
  if (blockIdx.x < 192) { out[i] = pos[i]; return; }
  int j = i - 192*256;
  int c = j & (CC2-1);
  const float invc = 1.0f / (float)TOTROWS;
  float mean = stats2[c] * invc;
  float var  = stats2[128 + c] * invc - mean*mean;
  float sc = rsqrtf(var + 1e-5f) * g2[c];
  float sh = be2[c] - mean * sc;
  float* out_nf = out + (size_t)BB*NN*3;
  float x = out_nf[j];
  out_nf[j] = fmaxf(fmaf(x, sc, sh), 0.f);
}

extern "C" void kernel_launch(void* const* d_in, const int* in_sizes, int n_in,
                              void* d_out, int out_size, void* d_ws, size_t ws_size,
                              hipStream_t stream) {
  const float* pos  = (const float*)d_in[0];
  const float* feat = (const float*)d_in[1];
  const float* W1   = (const float*)d_in[2];
  const float* g1   = (const float*)d_in[3];
  const float* be1  = (const float*)d_in[4];
  const float* W2   = (const float*)d_in[5];
  const float* g2   = (const float*)d_in[6];
  const float* be2  = (const float*)d_in[7];
  float* out = (float*)d_out;
  float* out_nf = out + (size_t)BB*NN*3;

  char* w = (char*)d_ws;
  int*   idx    = (int*)w;                       // 2 MB @ 0
  float* A      = (float*)(w + 0x200000);        // 320
  float* mom    = A + 320;                       // 16
  float* stats2 = mom + 16;                      // 256
  float* sc1    = stats2 + 256;                  // 64
  float* sh1    = sc1 + 64;                      // 64
  float* W1s    = sh1 + 64;                      // 192
  float* cnt    = (float*)(w + 0x210000);        // 16384 each
  float* DXa    = cnt + SITES;
  float* DYa    = DXa + SITES;
  float* DZa    = DYa + SITES;
  // Partials: 256 sets x 2048 f32 = 2 MB each, 8 MB total @ 0x260000.
  // They ALIAS g (4 MB @ 0x260000): partials are dead after kR_reduce,
  // and g is written only afterwards by kB_g. Footprint unchanged (0xA60000).
  float* Pc     = (float*)(w + 0x260000);
  float* Px     = Pc + (size_t)PSLICES*NN;
  float* Py     = Px + (size_t)PSLICES*NN;
  float* Pz     = Py + (size_t)PSLICES*NN;       // ends 0xA60000
  float* g      = (float*)(w + 0x260000);        // 4 MB (reuses partial space)

  hipMemsetAsync(A, 0, (320 + 16 + 256)*sizeof(float), stream);
  k1_ball   <<<512, 256, 0, stream>>>(pos, idx);
  kP_scatter<<<256, 1024, 0, stream>>>(pos, idx, Pc, Px, Py, Pz, mom);
  kR_reduce <<<256, 256, 0, stream>>>(Pc, Px, Py, Pz, cnt, DXa, DYa, DZa);
  kB_g      <<<128, 256, 0, stream>>>(feat, W1, cnt, DXa, DYa, DZa, g, A);
  kS_fold   <<<1, 256, 0, stream>>>(W1, g1, be1, A, mom, sc1, sh1, W1s);
  kD_mfma   <<<1024, 256, 0, stream>>>(pos, idx, g, sc1, sh1, W1s, W2,
                                       stats2, out_nf);
  k45_epi   <<<192 + (SITES*CC2)/256, 256, 0, stream>>>(pos, g2, be2, stats2, out);
}